// Round 6
// baseline (513.293 us; speedup 1.0000x reference)
//
#include <hip/hip_runtime.h>

// ShiftedWindowAttention on MI355X (gfx950) — fused, register-resident attention.
// B=16, H=W=112, C=256, NH=8, hd=32, window 7x7 (N=49), shift 3, nWin=4096.
// 512-thread block per window; wave wid owns head wid (channels [32wid,32wid+32)).
// Swapped QKV GEMMs leave q/k (and V via unswapped GEMM) in exactly the
// mfma_16x16x16 fragment layouts -> QK^T/softmax/PV run entirely in registers.
// This revision targets 4 waves/SIMD (2 blocks/CU): weights streamed 2-deep in
// the k-loops (no 64-reg hoist), S^T computed column-wise (no 64-reg st tile).
// LDS = 32 KB: X staging (per phase), then attention output for the final proj.

typedef short  bf16x4_t __attribute__((ext_vector_type(4)));
typedef short  bf16x8_t __attribute__((ext_vector_type(8)));
typedef float  f32x4_t  __attribute__((ext_vector_type(4)));
typedef int    i32x4_t  __attribute__((ext_vector_type(4)));

#define HH    112
#define WWDIM 112
#define NTOK  49
#define NWIN  4096
#define SHIFT 3

__device__ __forceinline__ unsigned short f2bf(float f) {
  unsigned u = __builtin_bit_cast(unsigned, f);
  u += 0x7FFFu + ((u >> 16) & 1u);           // RNE
  return (unsigned short)(u >> 16);
}

__device__ __forceinline__ bf16x8_t ld8(const unsigned short* p) {
  return __builtin_bit_cast(bf16x8_t, *reinterpret_cast<const i32x4_t*>(p));
}

__device__ __forceinline__ bf16x4_t pack4(float a, float b, float c, float d) {
  union { unsigned short u[4]; bf16x4_t v; } t;
  t.u[0] = f2bf(a); t.u[1] = f2bf(b); t.u[2] = f2bf(c); t.u[3] = f2bf(d);
  return t.v;
}

// XOR-swizzled index (ushort units) shared by writer+reader. rowElems = bf16/row.
__device__ __forceinline__ int swzi(int row, int col, int rowElems) {
  int by = col << 1;
  int sb = (((by >> 4) ^ (row & 7)) << 4) | (by & 15);
  return row * rowElems + (sb >> 1);
}

// ---------------- prep: weights -> bf16, bias table transposed to [h][kt][qt] ----------------
__global__ void prep_kernel(const float* __restrict__ Qw, const float* __restrict__ Kw,
                            const float* __restrict__ Vw, const float* __restrict__ Pw,
                            const float* __restrict__ rpb, const int* __restrict__ rpi,
                            unsigned short* __restrict__ wbf, float* __restrict__ biasT) {
  int idx = blockIdx.x * 256 + threadIdx.x;
  if (idx < 4 * 65536) {
    int which = idx >> 16, e = idx & 65535;
    const float* s = (which == 0) ? Qw : (which == 1) ? Kw : (which == 2) ? Vw : Pw;
    wbf[idx] = f2bf(s[e]);
  }
  if (idx < 8 * NTOK * NTOK) {
    int h = idx / (NTOK * NTOK), ij = idx % (NTOK * NTOK);
    int i = ij / NTOK, j = ij - (ij / NTOK) * NTOK;   // i = query tok, j = key tok
    biasT[h * (NTOK * NTOK) + j * NTOK + i] = rpb[rpi[ij] * 8 + h];
  }
}

#define GLOAD(SRC)                                                            \
  do {                                                                        \
    _Pragma("unroll") for (int it = 0; it < 8; ++it) {                        \
      g[it] = ((wid + (it << 3)) < NTOK)                                      \
                  ? *reinterpret_cast<const float4*>((SRC) + goff[it])        \
                  : make_float4(0.f, 0.f, 0.f, 0.f);                          \
    }                                                                         \
  } while (0)

#define XWRITE()                                                              \
  do {                                                                        \
    _Pragma("unroll") for (int it = 0; it < 8; ++it) {                        \
      unsigned v0 = (unsigned)f2bf(g[it].x) | ((unsigned)f2bf(g[it].y) << 16);\
      unsigned v1 = (unsigned)f2bf(g[it].z) | ((unsigned)f2bf(g[it].w) << 16);\
      *reinterpret_cast<uint2*>(                                              \
          &Xs[swzi(wid + (it << 3), lane << 2, 256)]) = make_uint2(v0, v1);   \
    }                                                                         \
  } while (0)

// streamed weight fragment load for step ks into slot s of the 2-deep ring
#define WLOAD(WP, KS, S)                                                      \
  do {                                                                        \
    _Pragma("unroll") for (int t = 0; t < 2; ++t)                             \
      bwr[S][t] = ld8(&(WP)[(((wid << 5) + (t << 4) + lo) << 8) +             \
                            ((KS) << 5) + kof]);                              \
  } while (0)

__global__ __launch_bounds__(512, 4) void fused_kernel(
    const float* __restrict__ Qin, const float* __restrict__ Kin, const float* __restrict__ Vin,
    const float* __restrict__ Qbv, const float* __restrict__ Kbv, const float* __restrict__ Vbv,
    const float* __restrict__ Pbv,
    const unsigned short* __restrict__ wbf, const float* __restrict__ biasT,
    float* __restrict__ out) {
  __shared__ unsigned short Xs[64 * 256];   // X staging per phase; then attn-out

  const int blk = blockIdx.x, tid = threadIdx.x;
  const int lane = tid & 63, wid = tid >> 6;            // 8 waves, head wid
  const int b = blk >> 8, wi = (blk >> 4) & 15, wj = blk & 15;
  const int lo = lane & 15, hi = lane >> 4;
  const int g4 = hi << 2, kof = hi << 3;

  // gather geometry (roll by SHIFT); wave handles rows wid+8*it
  unsigned goff[8];
#pragma unroll
  for (int it = 0; it < 8; ++it) {
    int row = wid + (it << 3);
    unsigned off = 0;
    if (row < NTOK) {
      int i = row / 7, j = row - i * 7;
      int h_ = wi * 7 + i + SHIFT; if (h_ >= HH) h_ -= HH;
      int w_ = wj * 7 + j + SHIFT; if (w_ >= WWDIM) w_ -= WWDIM;
      off = ((unsigned)((b * HH + h_) * WWDIM + w_) << 8) + (lane << 2);
    }
    goff[it] = off;
  }

  float4 g[8];
  bf16x8_t bwr[2][2];
  bf16x4_t qf[2][4], kf[2][4], vf[4][2];

  GLOAD(Qin);
  XWRITE();
  __syncthreads();

  // ---------------- Q and K projections (swapped: D[ch][tok]) ----------------
#pragma unroll
  for (int ph = 0; ph < 2; ++ph) {
    GLOAD(ph == 0 ? Kin : Vin);   // prefetch next staging while GEMM runs
    const unsigned short* W_ = wbf + (ph << 16);
    f32x4_t acc[2][4];
#pragma unroll
    for (int a = 0; a < 2; ++a)
#pragma unroll
      for (int c = 0; c < 4; ++c) acc[a][c] = (f32x4_t){0.f, 0.f, 0.f, 0.f};
    WLOAD(W_, 0, 0);
#pragma unroll
    for (int ks = 0; ks < 8; ++ks) {
      if (ks < 7) WLOAD(W_, ks + 1, (ks + 1) & 1);
      const int kk = (ks << 5) + kof;
      bf16x8_t xb[4];
#pragma unroll
      for (int nj = 0; nj < 4; ++nj) xb[nj] = ld8(&Xs[swzi((nj << 4) + lo, kk, 256)]);
#pragma unroll
      for (int mi = 0; mi < 2; ++mi)
#pragma unroll
        for (int nj = 0; nj < 4; ++nj)
          acc[mi][nj] = __builtin_amdgcn_mfma_f32_16x16x32_bf16(bwr[ks & 1][mi], xb[nj], acc[mi][nj], 0, 0, 0);
    }
    const float* bias = (ph == 0) ? Qbv : Kbv;
    const float scale = (ph == 0) ? 0.17677669529663687f : 1.0f;
    bf16x4_t (*dst)[4] = (ph == 0) ? qf : kf;
#pragma unroll
    for (int mi = 0; mi < 2; ++mi) {
      const float4 bb = *reinterpret_cast<const float4*>(bias + (wid << 5) + (mi << 4) + g4);
#pragma unroll
      for (int nj = 0; nj < 4; ++nj)
        dst[mi][nj] = pack4((acc[mi][nj][0] + bb.x) * scale, (acc[mi][nj][1] + bb.y) * scale,
                            (acc[mi][nj][2] + bb.z) * scale, (acc[mi][nj][3] + bb.w) * scale);
    }
    __syncthreads();
    XWRITE();
    __syncthreads();
  }

  // ---------------- V projection (unswapped: D[tok][ch]) ----------------
  {
    const unsigned short* W_ = wbf + (2 << 16);
    f32x4_t acc[4][2];
#pragma unroll
    for (int a = 0; a < 4; ++a)
#pragma unroll
      for (int c = 0; c < 2; ++c) acc[a][c] = (f32x4_t){0.f, 0.f, 0.f, 0.f};
    WLOAD(W_, 0, 0);
#pragma unroll
    for (int ks = 0; ks < 8; ++ks) {
      if (ks < 7) WLOAD(W_, ks + 1, (ks + 1) & 1);
      const int kk = (ks << 5) + kof;
      bf16x8_t xa[4];
#pragma unroll
      for (int mi = 0; mi < 4; ++mi) xa[mi] = ld8(&Xs[swzi((mi << 4) + lo, kk, 256)]);
#pragma unroll
      for (int mi = 0; mi < 4; ++mi)
#pragma unroll
        for (int t = 0; t < 2; ++t)
          acc[mi][t] = __builtin_amdgcn_mfma_f32_16x16x32_bf16(xa[mi], bwr[ks & 1][t], acc[mi][t], 0, 0, 0);
    }
    float bbv[2];
#pragma unroll
    for (int t = 0; t < 2; ++t) bbv[t] = Vbv[(wid << 5) + (t << 4) + lo];
#pragma unroll
    for (int mi = 0; mi < 4; ++mi)
#pragma unroll
      for (int t = 0; t < 2; ++t)
        vf[mi][t] = pack4(acc[mi][t][0] + bbv[t], acc[mi][t][1] + bbv[t],
                          acc[mi][t][2] + bbv[t], acc[mi][t][3] + bbv[t]);
  }

  // ---------------- attention, fully in registers ----------------
  const bool wi15 = (wi == 15), wj15 = (wj == 15);
  // key-token bits per (njk, rg): kt = 16*njk + 4*hi + rg
  unsigned kbi = 0, kbj = 0, kval = 0;
#pragma unroll
  for (int njk = 0; njk < 4; ++njk)
#pragma unroll
    for (int rg = 0; rg < 4; ++rg) {
      int kt = (njk << 4) + g4 + rg;
      if (kt < NTOK) {
        int ti = kt / 7, tj = kt - (kt / 7) * 7;
        unsigned bit = 1u << (njk * 4 + rg);
        kval |= bit;
        if (ti >= 4) kbi |= bit;
        if (tj >= 4) kbj |= bit;
      }
    }

  // per-column S^T + softmax: column qt-block njq at a time (16-reg st slice)
  const float* bh = biasT + wid * (NTOK * NTOK);
  bf16x4_t pf[4][4];
#pragma unroll
  for (int njq = 0; njq < 4; ++njq) {
    f32x4_t stc[4];
    __builtin_amdgcn_s_setprio(1);
#pragma unroll
    for (int njk = 0; njk < 4; ++njk) {
      stc[njk] = __builtin_amdgcn_mfma_f32_16x16x16bf16_1k(
          kf[0][njk], qf[0][njq], (f32x4_t){0.f, 0.f, 0.f, 0.f}, 0, 0, 0);
      stc[njk] = __builtin_amdgcn_mfma_f32_16x16x16bf16_1k(
          kf[1][njk], qf[1][njq], stc[njk], 0, 0, 0);
    }
    __builtin_amdgcn_s_setprio(0);

    const int qt = (njq << 4) + lo;
    const bool qv = qt < NTOK;
    const int sqt = qv ? qt : 0;
    const int qti = sqt / 7, qtj = sqt - (sqt / 7) * 7;
    const bool qbi = qti >= 4, qbj = qtj >= 4;
    float vals[4][4];
    float m = -3e38f;
#pragma unroll
    for (int njk = 0; njk < 4; ++njk)
#pragma unroll
      for (int rg = 0; rg < 4; ++rg) {
        const int bit = njk * 4 + rg;
        const int kt = (njk << 4) + g4 + rg;
        const bool valid = qv && ((kval >> bit) & 1u);
        float v = stc[njk][rg] + bh[(valid ? kt : 0) * NTOK + sqt];
        if (wi15 && (qbi != (bool)((kbi >> bit) & 1u))) v -= 100.f;
        if (wj15 && (qbj != (bool)((kbj >> bit) & 1u))) v -= 100.f;
        v = valid ? v : -1e30f;
        vals[njk][rg] = v;
        m = fmaxf(m, v);
      }
    m = fmaxf(m, __shfl_xor(m, 16));
    m = fmaxf(m, __shfl_xor(m, 32));
    float sum = 0.f;
#pragma unroll
    for (int njk = 0; njk < 4; ++njk)
#pragma unroll
      for (int rg = 0; rg < 4; ++rg) {
        const float e = __expf(vals[njk][rg] - m);
        vals[njk][rg] = e;
        sum += e;
      }
    sum += __shfl_xor(sum, 16);
    sum += __shfl_xor(sum, 32);
    const float inv = 1.f / sum;
#pragma unroll
    for (int njk = 0; njk < 4; ++njk)
      pf[njk][njq] = pack4(vals[njk][0] * inv, vals[njk][1] * inv,
                           vals[njk][2] * inv, vals[njk][3] * inv);
  }

  // PV: O^T[ch][qt] = sum_kt V^T[ch][kt] P^T[kt][qt] — frags straight from regs
  f32x4_t o[2][4];
#pragma unroll
  for (int a = 0; a < 2; ++a)
#pragma unroll
    for (int c = 0; c < 4; ++c) o[a][c] = (f32x4_t){0.f, 0.f, 0.f, 0.f};
  __builtin_amdgcn_s_setprio(1);
#pragma unroll
  for (int mi = 0; mi < 4; ++mi)
#pragma unroll
    for (int t = 0; t < 2; ++t)
#pragma unroll
      for (int njq = 0; njq < 4; ++njq)
        o[t][njq] = __builtin_amdgcn_mfma_f32_16x16x16bf16_1k(vf[mi][t], pf[mi][njq], o[t][njq], 0, 0, 0);
  __builtin_amdgcn_s_setprio(0);

  __syncthreads();   // all waves past their V-GEMM Xs reads -> reuse Xs as attn-out
#pragma unroll
  for (int t = 0; t < 2; ++t)
#pragma unroll
    for (int njq = 0; njq < 4; ++njq) {
      const int qt = (njq << 4) + lo;
      const int ch0 = (wid << 5) + (t << 4) + g4;
      unsigned u0 = (unsigned)f2bf(o[t][njq][0]) | ((unsigned)f2bf(o[t][njq][1]) << 16);
      unsigned u1 = (unsigned)f2bf(o[t][njq][2]) | ((unsigned)f2bf(o[t][njq][3]) << 16);
      *reinterpret_cast<uint2*>(&Xs[swzi(qt, ch0, 256)]) = make_uint2(u0, u1);
    }
  __syncthreads();

  // ---------------- final projection (swapped) + scatter with inverse roll ----------------
  {
    const unsigned short* W_ = wbf + (3 << 16);
    f32x4_t y[2][4];
#pragma unroll
    for (int a = 0; a < 2; ++a)
#pragma unroll
      for (int c = 0; c < 4; ++c) y[a][c] = (f32x4_t){0.f, 0.f, 0.f, 0.f};
    WLOAD(W_, 0, 0);
#pragma unroll
    for (int ks = 0; ks < 8; ++ks) {
      if (ks < 7) WLOAD(W_, ks + 1, (ks + 1) & 1);
      const int kk = (ks << 5) + kof;
      bf16x8_t xb[4];
#pragma unroll
      for (int nj = 0; nj < 4; ++nj) xb[nj] = ld8(&Xs[swzi((nj << 4) + lo, kk, 256)]);
#pragma unroll
      for (int mi = 0; mi < 2; ++mi)
#pragma unroll
        for (int nj = 0; nj < 4; ++nj)
          y[mi][nj] = __builtin_amdgcn_mfma_f32_16x16x32_bf16(bwr[ks & 1][mi], xb[nj], y[mi][nj], 0, 0, 0);
    }
    float4 pb[2];
#pragma unroll
    for (int mi = 0; mi < 2; ++mi)
      pb[mi] = *reinterpret_cast<const float4*>(Pbv + (wid << 5) + (mi << 4) + g4);
#pragma unroll
    for (int nj = 0; nj < 4; ++nj) {
      const int tok = (nj << 4) + lo;
      if (tok < NTOK) {
        const int i = tok / 7, j = tok - (tok / 7) * 7;
        int h_ = wi * 7 + i + SHIFT; if (h_ >= HH) h_ -= HH;
        int w_ = wj * 7 + j + SHIFT; if (w_ >= WWDIM) w_ -= WWDIM;
        float* ob = out + ((size_t)((b * HH + h_) * WWDIM + w_) << 8);
#pragma unroll
        for (int mi = 0; mi < 2; ++mi) {
          const int ch0 = (wid << 5) + (mi << 4) + g4;
          *reinterpret_cast<float4*>(ob + ch0) =
              make_float4(y[mi][nj][0] + pb[mi].x, y[mi][nj][1] + pb[mi].y,
                          y[mi][nj][2] + pb[mi].z, y[mi][nj][3] + pb[mi].w);
        }
      }
    }
  }
}

extern "C" void kernel_launch(void* const* d_in, const int* in_sizes, int n_in,
                              void* d_out, int out_size, void* d_ws, size_t ws_size,
                              hipStream_t stream) {
  const float* Q   = (const float*)d_in[0];
  const float* K   = (const float*)d_in[1];
  const float* V   = (const float*)d_in[2];
  const float* Qw  = (const float*)d_in[3];
  const float* Qb  = (const float*)d_in[4];
  const float* Kw  = (const float*)d_in[5];
  const float* Kb  = (const float*)d_in[6];
  const float* Vw  = (const float*)d_in[7];
  const float* Vb  = (const float*)d_in[8];
  const float* Pw  = (const float*)d_in[9];
  const float* Pb  = (const float*)d_in[10];
  const float* rpb = (const float*)d_in[11];
  const int*   rpi = (const int*)d_in[12];

  unsigned short* wbf = (unsigned short*)d_ws;                 // 4*65536 bf16
  float* biasT = (float*)(wbf + 4 * 65536);                    // 8*49*49 f32 (transposed)

  const size_t need = (size_t)4 * 65536 * 2 + (size_t)8 * NTOK * NTOK * 4;
  if (ws_size < need) return;  // loud failure signal (output stays poisoned)

  prep_kernel<<<1024, 256, 0, stream>>>(Qw, Kw, Vw, Pw, rpb, rpi, wbf, biasT);
  fused_kernel<<<NWIN, 512, 0, stream>>>(Q, K, V, Qb, Kb, Vb, Pb, wbf, biasT,
                                         (float*)d_out);
}

// Round 7
// 448.166 us; speedup vs baseline: 1.1453x; 1.1453x over previous
//
#include <hip/hip_runtime.h>

// ShiftedWindowAttention on MI355X (gfx950) — fused, register-resident attention.
// B=16, H=W=112, C=256, NH=8, hd=32, window 7x7 (N=49), shift 3, nWin=4096.
// 512-thread block per window; wave wid owns head wid (channels [32wid,32wid+32)).
// Swapped QKV GEMMs leave q/k (and V via unswapped GEMM) in exactly the
// mfma_16x16x16 fragment layouts -> QK^T/softmax/PV run entirely in registers.
// R7: back to 2 waves/SIMD (hoisted weights, no spill), double-buffered Xs
// (4 barriers total), float4 softmax-bias loads, cvt_pk_bf16 + exp2 VALU diet.
// LDS = 64 KB: Xs[2] staging; Xs[1] reused for attn-out before final proj.

typedef short  bf16x4_t __attribute__((ext_vector_type(4)));
typedef short  bf16x8_t __attribute__((ext_vector_type(8)));
typedef float  f32x4_t  __attribute__((ext_vector_type(4)));
typedef int    i32x4_t  __attribute__((ext_vector_type(4)));

#define HH    112
#define WWDIM 112
#define NTOK  49
#define NWIN  4096
#define SHIFT 3
#define LOG2E 1.4426950408889634f
#define MASKS (-144.26950408889634f)   // -100 * log2e

__device__ __forceinline__ unsigned short f2bf(float f) {   // prep only
  unsigned u = __builtin_bit_cast(unsigned, f);
  u += 0x7FFFu + ((u >> 16) & 1u);
  return (unsigned short)(u >> 16);
}

__device__ __forceinline__ unsigned cvtpk(float a, float b) {  // lo=a, hi=b (RNE)
  unsigned r;
  asm("v_cvt_pk_bf16_f32 %0, %1, %2" : "=v"(r) : "v"(a), "v"(b));
  return r;
}

__device__ __forceinline__ float exp2fast(float x) {
  float r;
  asm("v_exp_f32 %0, %1" : "=v"(r) : "v"(x));
  return r;
}

__device__ __forceinline__ bf16x8_t ld8(const unsigned short* p) {
  return __builtin_bit_cast(bf16x8_t, *reinterpret_cast<const i32x4_t*>(p));
}

__device__ __forceinline__ bf16x4_t pack4(float a, float b, float c, float d) {
  union { unsigned u[2]; bf16x4_t v; } t;
  t.u[0] = cvtpk(a, b); t.u[1] = cvtpk(c, d);
  return t.v;
}

// XOR-swizzled index (ushort units) shared by writer+reader. rowElems = bf16/row.
__device__ __forceinline__ int swzi(int row, int col, int rowElems) {
  int by = col << 1;
  int sb = (((by >> 4) ^ (row & 7)) << 4) | (by & 15);
  return row * rowElems + (sb >> 1);
}

// ---- prep: weights -> bf16; bias table [h][qt][64pad], pre-scaled by log2e ----
__global__ void prep_kernel(const float* __restrict__ Qw, const float* __restrict__ Kw,
                            const float* __restrict__ Vw, const float* __restrict__ Pw,
                            const float* __restrict__ rpb, const int* __restrict__ rpi,
                            unsigned short* __restrict__ wbf, float* __restrict__ biasP) {
  int idx = blockIdx.x * 256 + threadIdx.x;
  if (idx < 4 * 65536) {
    int which = idx >> 16, e = idx & 65535;
    const float* s = (which == 0) ? Qw : (which == 1) ? Kw : (which == 2) ? Vw : Pw;
    wbf[idx] = f2bf(s[e]);
  }
  if (idx < 8 * 49 * 64) {
    int h = idx / 3136, r = idx - h * 3136;
    int i = r >> 6, j = r & 63;   // i = query tok, j = key tok (padded to 64)
    biasP[idx] = (i < NTOK && j < NTOK) ? rpb[rpi[i * NTOK + j] * 8 + h] * LOG2E : 0.f;
  }
}

#define GLOAD(SRC)                                                            \
  do {                                                                        \
    _Pragma("unroll") for (int it = 0; it < 8; ++it) {                        \
      g[it] = ((wid + (it << 3)) < NTOK)                                      \
                  ? *reinterpret_cast<const float4*>((SRC) + goff[it])        \
                  : make_float4(0.f, 0.f, 0.f, 0.f);                          \
    }                                                                         \
  } while (0)

#define XWRITE(B)                                                             \
  do {                                                                        \
    _Pragma("unroll") for (int it = 0; it < 8; ++it) {                        \
      unsigned v0 = cvtpk(g[it].x, g[it].y);                                  \
      unsigned v1 = cvtpk(g[it].z, g[it].w);                                  \
      *reinterpret_cast<uint2*>(                                              \
          &Xs[B][swzi(wid + (it << 3), lane << 2, 256)]) = make_uint2(v0, v1);\
    }                                                                         \
  } while (0)

// hoist one weight matrix's wave-slice (32 rows x 256 K) into bw[8][2]
#define WHOIST(PH)                                                            \
  do {                                                                        \
    const unsigned short* W_ = wbf + ((PH) << 16);                            \
    _Pragma("unroll") for (int ks = 0; ks < 8; ++ks)                          \
        _Pragma("unroll") for (int t = 0; t < 2; ++t)                         \
            bw[ks][t] =                                                       \
        ld8(&W_[(((wid << 5) + (t << 4) + lo) << 8) + (ks << 5) + kof]);      \
  } while (0)

__global__ __launch_bounds__(512, 2) void fused_kernel(
    const float* __restrict__ Qin, const float* __restrict__ Kin, const float* __restrict__ Vin,
    const float* __restrict__ Qbv, const float* __restrict__ Kbv, const float* __restrict__ Vbv,
    const float* __restrict__ Pbv,
    const unsigned short* __restrict__ wbf, const float* __restrict__ biasP,
    float* __restrict__ out) {
  __shared__ unsigned short Xs[2][64 * 256];   // double-buffered staging / attn-out

  const int blk = blockIdx.x, tid = threadIdx.x;
  const int lane = tid & 63, wid = tid >> 6;            // 8 waves, head wid
  const int b = blk >> 8, wi = (blk >> 4) & 15, wj = blk & 15;
  const int lo = lane & 15, hi = lane >> 4;
  const int g4 = hi << 2, kof = hi << 3;

  // gather geometry (roll by SHIFT); wave handles rows wid+8*it
  unsigned goff[8];
#pragma unroll
  for (int it = 0; it < 8; ++it) {
    int row = wid + (it << 3);
    unsigned off = 0;
    if (row < NTOK) {
      int i = row / 7, j = row - i * 7;
      int h_ = wi * 7 + i + SHIFT; if (h_ >= HH) h_ -= HH;
      int w_ = wj * 7 + j + SHIFT; if (w_ >= WWDIM) w_ -= WWDIM;
      off = ((unsigned)((b * HH + h_) * WWDIM + w_) << 8) + (lane << 2);
    }
    goff[it] = off;
  }

  float4 g[8];
  bf16x8_t bw[8][2];
  bf16x4_t qf[2][4], kf[2][4], vf[4][2];

  GLOAD(Qin);
  XWRITE(0);
  WHOIST(0);
  __syncthreads();

  // ---------------- Q and K projections (swapped: D[ch][tok]) ----------------
#pragma unroll
  for (int ph = 0; ph < 2; ++ph) {
    GLOAD(ph == 0 ? Kin : Vin);   // prefetch next staging while GEMM runs
    const unsigned short* Xb = Xs[ph];
    f32x4_t acc[2][4];
#pragma unroll
    for (int a = 0; a < 2; ++a)
#pragma unroll
      for (int c = 0; c < 4; ++c) acc[a][c] = (f32x4_t){0.f, 0.f, 0.f, 0.f};
#pragma unroll
    for (int ks = 0; ks < 8; ++ks) {
      const int kk = (ks << 5) + kof;
      bf16x8_t xb[4];
#pragma unroll
      for (int nj = 0; nj < 4; ++nj) xb[nj] = ld8(&Xb[swzi((nj << 4) + lo, kk, 256)]);
#pragma unroll
      for (int mi = 0; mi < 2; ++mi)
#pragma unroll
        for (int nj = 0; nj < 4; ++nj)
          acc[mi][nj] = __builtin_amdgcn_mfma_f32_16x16x32_bf16(bw[ks][mi], xb[nj], acc[mi][nj], 0, 0, 0);
    }
    const float* bias = (ph == 0) ? Qbv : Kbv;
    const float scale = (ph == 0) ? 0.17677669529663687f * LOG2E : 1.0f;  // hd^-0.5*log2e on q
    bf16x4_t (*dst)[4] = (ph == 0) ? qf : kf;
#pragma unroll
    for (int mi = 0; mi < 2; ++mi) {
      const float4 bb = *reinterpret_cast<const float4*>(bias + (wid << 5) + (mi << 4) + g4);
#pragma unroll
      for (int nj = 0; nj < 4; ++nj)
        dst[mi][nj] = pack4((acc[mi][nj][0] + bb.x) * scale, (acc[mi][nj][1] + bb.y) * scale,
                            (acc[mi][nj][2] + bb.z) * scale, (acc[mi][nj][3] + bb.w) * scale);
    }
    XWRITE(ph ^ 1);     // K -> buf1 (while Q GEMM read buf0), V -> buf0
    WHOIST(ph + 1);
    __syncthreads();
  }

  // ---------------- V projection (unswapped: D[tok][ch]) from buf0 ----------------
  {
    const unsigned short* Xb = Xs[0];
    f32x4_t acc[4][2];
#pragma unroll
    for (int a = 0; a < 4; ++a)
#pragma unroll
      for (int c = 0; c < 2; ++c) acc[a][c] = (f32x4_t){0.f, 0.f, 0.f, 0.f};
#pragma unroll
    for (int ks = 0; ks < 8; ++ks) {
      const int kk = (ks << 5) + kof;
      bf16x8_t xa[4];
#pragma unroll
      for (int mi = 0; mi < 4; ++mi) xa[mi] = ld8(&Xb[swzi((mi << 4) + lo, kk, 256)]);
#pragma unroll
      for (int mi = 0; mi < 4; ++mi)
#pragma unroll
        for (int t = 0; t < 2; ++t)
          acc[mi][t] = __builtin_amdgcn_mfma_f32_16x16x32_bf16(xa[mi], bw[ks][t], acc[mi][t], 0, 0, 0);
    }
    float bbv[2];
#pragma unroll
    for (int t = 0; t < 2; ++t) bbv[t] = Vbv[(wid << 5) + (t << 4) + lo];
#pragma unroll
    for (int mi = 0; mi < 4; ++mi)
#pragma unroll
      for (int t = 0; t < 2; ++t)
        vf[mi][t] = pack4(acc[mi][t][0] + bbv[t], acc[mi][t][1] + bbv[t],
                          acc[mi][t][2] + bbv[t], acc[mi][t][3] + bbv[t]);
  }
  WHOIST(3);   // Pw hoist overlaps attention

  // ---------------- attention, fully in registers ----------------
  const bool wi15 = (wi == 15), wj15 = (wj == 15);
  // key-token bits per (njk, rg): kt = 16*njk + 4*hi + rg
  unsigned kbi = 0, kbj = 0, kval = 0;
#pragma unroll
  for (int njk = 0; njk < 4; ++njk)
#pragma unroll
    for (int rg = 0; rg < 4; ++rg) {
      int kt = (njk << 4) + g4 + rg;
      if (kt < NTOK) {
        int ti = kt / 7, tj = kt - (kt / 7) * 7;
        unsigned bit = 1u << (njk * 4 + rg);
        kval |= bit;
        if (ti >= 4) kbi |= bit;
        if (tj >= 4) kbj |= bit;
      }
    }

  // per-column S^T + softmax: column qt-block njq at a time (16-reg st slice)
  bf16x4_t pf[4][4];
#pragma unroll
  for (int njq = 0; njq < 4; ++njq) {
    const int qt = (njq << 4) + lo;
    const bool qv = qt < NTOK;
    const int sqt = qv ? qt : 0;
    // bias row for this lane's qt: 4 aligned float4 loads (issue before MFMAs)
    const float* bq = biasP + wid * 3136 + (sqt << 6);
    f32x4_t bfr[4];
#pragma unroll
    for (int njk = 0; njk < 4; ++njk)
      bfr[njk] = *reinterpret_cast<const f32x4_t*>(bq + (njk << 4) + g4);

    f32x4_t stc[4];
    __builtin_amdgcn_s_setprio(1);
#pragma unroll
    for (int njk = 0; njk < 4; ++njk) {
      stc[njk] = __builtin_amdgcn_mfma_f32_16x16x16bf16_1k(
          kf[0][njk], qf[0][njq], (f32x4_t){0.f, 0.f, 0.f, 0.f}, 0, 0, 0);
      stc[njk] = __builtin_amdgcn_mfma_f32_16x16x16bf16_1k(
          kf[1][njk], qf[1][njq], stc[njk], 0, 0, 0);
    }
    __builtin_amdgcn_s_setprio(0);

    const int qti = sqt / 7, qtj = sqt - (sqt / 7) * 7;
    const bool qbi = qti >= 4, qbj = qtj >= 4;
    float vals[4][4];
    float m = -3e38f;
#pragma unroll
    for (int njk = 0; njk < 4; ++njk)
#pragma unroll
      for (int rg = 0; rg < 4; ++rg) {
        const int bit = njk * 4 + rg;
        const bool valid = qv && ((kval >> bit) & 1u);
        float v = stc[njk][rg] + bfr[njk][rg];
        if (wi15 && (qbi != (bool)((kbi >> bit) & 1u))) v += MASKS;
        if (wj15 && (qbj != (bool)((kbj >> bit) & 1u))) v += MASKS;
        v = valid ? v : -1e30f;
        vals[njk][rg] = v;
        m = fmaxf(m, v);
      }
    m = fmaxf(m, __shfl_xor(m, 16));
    m = fmaxf(m, __shfl_xor(m, 32));
    float sum = 0.f;
#pragma unroll
    for (int njk = 0; njk < 4; ++njk)
#pragma unroll
      for (int rg = 0; rg < 4; ++rg) {
        const float e = exp2fast(vals[njk][rg] - m);
        vals[njk][rg] = e;
        sum += e;
      }
    sum += __shfl_xor(sum, 16);
    sum += __shfl_xor(sum, 32);
    const float inv = __builtin_amdgcn_rcpf(sum);
#pragma unroll
    for (int njk = 0; njk < 4; ++njk)
      pf[njk][njq] = pack4(vals[njk][0] * inv, vals[njk][1] * inv,
                           vals[njk][2] * inv, vals[njk][3] * inv);
  }

  // PV: O^T[ch][qt] = sum_kt V^T[ch][kt] P^T[kt][qt] — frags straight from regs
  f32x4_t o[2][4];
#pragma unroll
  for (int a = 0; a < 2; ++a)
#pragma unroll
    for (int c = 0; c < 4; ++c) o[a][c] = (f32x4_t){0.f, 0.f, 0.f, 0.f};
  __builtin_amdgcn_s_setprio(1);
#pragma unroll
  for (int mi = 0; mi < 4; ++mi)
#pragma unroll
    for (int t = 0; t < 2; ++t)
#pragma unroll
      for (int njq = 0; njq < 4; ++njq)
        o[t][njq] = __builtin_amdgcn_mfma_f32_16x16x16bf16_1k(vf[mi][t], pf[mi][njq], o[t][njq], 0, 0, 0);
  __builtin_amdgcn_s_setprio(0);

  // attn-out -> Xs[1] (buf1's last readers finished before the pre-V barrier)
#pragma unroll
  for (int t = 0; t < 2; ++t)
#pragma unroll
    for (int njq = 0; njq < 4; ++njq) {
      const int qt = (njq << 4) + lo;
      const int ch0 = (wid << 5) + (t << 4) + g4;
      *reinterpret_cast<uint2*>(&Xs[1][swzi(qt, ch0, 256)]) =
          make_uint2(cvtpk(o[t][njq][0], o[t][njq][1]), cvtpk(o[t][njq][2], o[t][njq][3]));
    }
  __syncthreads();

  // ---------------- final projection (swapped) + scatter with inverse roll ----------------
  {
    const unsigned short* Xb = Xs[1];
    f32x4_t y[2][4];
#pragma unroll
    for (int a = 0; a < 2; ++a)
#pragma unroll
      for (int c = 0; c < 4; ++c) y[a][c] = (f32x4_t){0.f, 0.f, 0.f, 0.f};
#pragma unroll
    for (int ks = 0; ks < 8; ++ks) {
      const int kk = (ks << 5) + kof;
      bf16x8_t xb[4];
#pragma unroll
      for (int nj = 0; nj < 4; ++nj) xb[nj] = ld8(&Xb[swzi((nj << 4) + lo, kk, 256)]);
#pragma unroll
      for (int mi = 0; mi < 2; ++mi)
#pragma unroll
        for (int nj = 0; nj < 4; ++nj)
          y[mi][nj] = __builtin_amdgcn_mfma_f32_16x16x32_bf16(bw[ks][mi], xb[nj], y[mi][nj], 0, 0, 0);
    }
    float4 pb[2];
#pragma unroll
    for (int mi = 0; mi < 2; ++mi)
      pb[mi] = *reinterpret_cast<const float4*>(Pbv + (wid << 5) + (mi << 4) + g4);
#pragma unroll
    for (int nj = 0; nj < 4; ++nj) {
      const int tok = (nj << 4) + lo;
      if (tok < NTOK) {
        const int i = tok / 7, j = tok - (tok / 7) * 7;
        int h_ = wi * 7 + i + SHIFT; if (h_ >= HH) h_ -= HH;
        int w_ = wj * 7 + j + SHIFT; if (w_ >= WWDIM) w_ -= WWDIM;
        float* ob = out + ((size_t)((b * HH + h_) * WWDIM + w_) << 8);
#pragma unroll
        for (int mi = 0; mi < 2; ++mi) {
          const int ch0 = (wid << 5) + (mi << 4) + g4;
          *reinterpret_cast<float4*>(ob + ch0) =
              make_float4(y[mi][nj][0] + pb[mi].x, y[mi][nj][1] + pb[mi].y,
                          y[mi][nj][2] + pb[mi].z, y[mi][nj][3] + pb[mi].w);
        }
      }
    }
  }
}

extern "C" void kernel_launch(void* const* d_in, const int* in_sizes, int n_in,
                              void* d_out, int out_size, void* d_ws, size_t ws_size,
                              hipStream_t stream) {
  const float* Q   = (const float*)d_in[0];
  const float* K   = (const float*)d_in[1];
  const float* V   = (const float*)d_in[2];
  const float* Qw  = (const float*)d_in[3];
  const float* Qb  = (const float*)d_in[4];
  const float* Kw  = (const float*)d_in[5];
  const float* Kb  = (const float*)d_in[6];
  const float* Vw  = (const float*)d_in[7];
  const float* Vb  = (const float*)d_in[8];
  const float* Pw  = (const float*)d_in[9];
  const float* Pb  = (const float*)d_in[10];
  const float* rpb = (const float*)d_in[11];
  const int*   rpi = (const int*)d_in[12];

  unsigned short* wbf = (unsigned short*)d_ws;                 // 4*65536 bf16
  float* biasP = (float*)(wbf + 4 * 65536);                    // 8*49*64 f32, log2e-scaled

  const size_t need = (size_t)4 * 65536 * 2 + (size_t)8 * 49 * 64 * 4;
  if (ws_size < need) return;  // loud failure signal (output stays poisoned)

  prep_kernel<<<1024, 256, 0, stream>>>(Qw, Kw, Vw, Pw, rpb, rpi, wbf, biasP);
  fused_kernel<<<NWIN, 512, 0, stream>>>(Q, K, V, Qb, Kb, Vb, Pb, wbf, biasP,
                                         (float*)d_out);
}

// Round 9
// 445.472 us; speedup vs baseline: 1.1522x; 1.0060x over previous
//
#include <hip/hip_runtime.h>

// ShiftedWindowAttention on MI355X (gfx950) — fused, register-resident attention.
// B=16, H=W=112, C=256, NH=8, hd=32, window 7x7 (N=49), shift 3, nWin=4096.
// R9: 256-thread / 4-wave blocks, one window each, 2 blocks/CU (two INDEPENDENT
// barrier domains per CU -> cross-block phase overlap). Wave wid owns channels
// [64wid,64wid+64) = heads 2wid, 2wid+1. Swapped QKV GEMMs leave q/k (and V via
// unswapped GEMM) in exactly the mfma_16x16x16 fragment layouts -> attention
// entirely in registers (R7-verified shape). Weights streamed 2-deep from L2.
// LDS = 64 KB: Xs[2] staging; Xs[1] reused for attn-out before final proj.

typedef short  bf16x4_t __attribute__((ext_vector_type(4)));
typedef short  bf16x8_t __attribute__((ext_vector_type(8)));
typedef float  f32x4_t  __attribute__((ext_vector_type(4)));
typedef int    i32x4_t  __attribute__((ext_vector_type(4)));

#define HH    112
#define WWDIM 112
#define NTOK  49
#define NWIN  4096
#define SHIFT 3
#define LOG2E 1.4426950408889634f
#define MASKS (-144.26950408889634f)   // -100 * log2e

__device__ __forceinline__ unsigned short f2bf(float f) {   // prep only
  unsigned u = __builtin_bit_cast(unsigned, f);
  u += 0x7FFFu + ((u >> 16) & 1u);
  return (unsigned short)(u >> 16);
}

__device__ __forceinline__ unsigned cvtpk(float a, float b) {  // lo=a, hi=b (RNE)
  unsigned r;
  asm("v_cvt_pk_bf16_f32 %0, %1, %2" : "=v"(r) : "v"(a), "v"(b));
  return r;
}

__device__ __forceinline__ float exp2fast(float x) {
  float r;
  asm("v_exp_f32 %0, %1" : "=v"(r) : "v"(x));
  return r;
}

__device__ __forceinline__ bf16x8_t ld8(const unsigned short* p) {
  return __builtin_bit_cast(bf16x8_t, *reinterpret_cast<const i32x4_t*>(p));
}

__device__ __forceinline__ bf16x4_t pack4(float a, float b, float c, float d) {
  union { unsigned u[2]; bf16x4_t v; } t;
  t.u[0] = cvtpk(a, b); t.u[1] = cvtpk(c, d);
  return t.v;
}

// XOR-swizzled index (ushort units) shared by writer+reader. rowElems = bf16/row.
__device__ __forceinline__ int swzi(int row, int col, int rowElems) {
  int by = col << 1;
  int sb = (((by >> 4) ^ (row & 7)) << 4) | (by & 15);
  return row * rowElems + (sb >> 1);
}

// ---- prep: weights -> bf16; bias table [h][qt][64pad], pre-scaled by log2e ----
__global__ void prep_kernel(const float* __restrict__ Qw, const float* __restrict__ Kw,
                            const float* __restrict__ Vw, const float* __restrict__ Pw,
                            const float* __restrict__ rpb, const int* __restrict__ rpi,
                            unsigned short* __restrict__ wbf, float* __restrict__ biasP) {
  int idx = blockIdx.x * 256 + threadIdx.x;
  if (idx < 4 * 65536) {
    int which = idx >> 16, e = idx & 65535;
    const float* s = (which == 0) ? Qw : (which == 1) ? Kw : (which == 2) ? Vw : Pw;
    wbf[idx] = f2bf(s[e]);
  }
  if (idx < 8 * 49 * 64) {
    int h = idx / 3136, r = idx - h * 3136;
    int i = r >> 6, j = r & 63;   // i = query tok, j = key tok (padded to 64)
    biasP[idx] = (i < NTOK && j < NTOK) ? rpb[rpi[i * NTOK + j] * 8 + h] * LOG2E : 0.f;
  }
}

#define GLOAD(SRC)                                                            \
  do {                                                                        \
    _Pragma("unroll") for (int it = 0; it < 16; ++it) {                       \
      g[it] = (((it << 2) + wid) < NTOK)                                      \
                  ? *reinterpret_cast<const float4*>((SRC) + goff[it])        \
                  : make_float4(0.f, 0.f, 0.f, 0.f);                          \
    }                                                                         \
  } while (0)

#define XWRITE(B)                                                             \
  do {                                                                        \
    _Pragma("unroll") for (int it = 0; it < 16; ++it) {                       \
      unsigned v0 = cvtpk(g[it].x, g[it].y);                                  \
      unsigned v1 = cvtpk(g[it].z, g[it].w);                                  \
      *reinterpret_cast<uint2*>(                                              \
          &Xs[B][swzi((it << 2) + wid, lane << 2, 256)]) = make_uint2(v0, v1);\
    }                                                                         \
  } while (0)

// streamed weight fragment load (wave's 64 rows x 32 k) into slot S of 2-deep ring
#define WLOAD(WP, KS, S)                                                      \
  do {                                                                        \
    _Pragma("unroll") for (int m = 0; m < 4; ++m)                             \
      bwr[S][m] = ld8(&(WP)[(((wid << 6) + (m << 4) + lo) << 8) +             \
                            ((KS) << 5) + kof]);                              \
  } while (0)

__global__ __launch_bounds__(256, 2) void fused_kernel(
    const float* __restrict__ Qin, const float* __restrict__ Kin, const float* __restrict__ Vin,
    const float* __restrict__ Qbv, const float* __restrict__ Kbv, const float* __restrict__ Vbv,
    const float* __restrict__ Pbv,
    const unsigned short* __restrict__ wbf, const float* __restrict__ biasP,
    float* __restrict__ out) {
  __shared__ unsigned short Xs[2][64 * 256];   // double-buffered staging / attn-out

  const int blk = blockIdx.x, tid = threadIdx.x;
  const int lane = tid & 63, wid = tid >> 6;            // 4 waves
  const int b = blk >> 8, wi = (blk >> 4) & 15, wj = blk & 15;
  const int lo = lane & 15, hi = lane >> 4;
  const int g4 = hi << 2, kof = hi << 3;

  // gather geometry (roll by SHIFT); wave handles rows 4*it + wid
  unsigned goff[16];
#pragma unroll
  for (int it = 0; it < 16; ++it) {
    int row = (it << 2) + wid;
    unsigned off = 0;
    if (row < NTOK) {
      int i = row / 7, j = row - i * 7;
      int h_ = wi * 7 + i + SHIFT; if (h_ >= HH) h_ -= HH;
      int w_ = wj * 7 + j + SHIFT; if (w_ >= WWDIM) w_ -= WWDIM;
      off = ((unsigned)((b * HH + h_) * WWDIM + w_) << 8) + (lane << 2);
    }
    goff[it] = off;
  }

  float4 g[16];
  bf16x8_t bwr[2][4];
  bf16x4_t qf[4][4], kf[4][4], vf[4][4];

  GLOAD(Qin);
  XWRITE(0);
  __syncthreads();

  // ---------------- Q and K projections (swapped: D[ch][tok]) ----------------
#pragma unroll
  for (int ph = 0; ph < 2; ++ph) {
    GLOAD(ph == 0 ? Kin : Vin);   // prefetch next staging while GEMM runs
    const unsigned short* Xb = Xs[ph];
    const unsigned short* W_ = wbf + (ph << 16);
    f32x4_t acc[4][4];
#pragma unroll
    for (int a = 0; a < 4; ++a)
#pragma unroll
      for (int c = 0; c < 4; ++c) acc[a][c] = (f32x4_t){0.f, 0.f, 0.f, 0.f};
    WLOAD(W_, 0, 0);
#pragma unroll
    for (int ks = 0; ks < 8; ++ks) {
      if (ks < 7) WLOAD(W_, ks + 1, (ks + 1) & 1);
      const int kk = (ks << 5) + kof;
      bf16x8_t xb[4];
#pragma unroll
      for (int nj = 0; nj < 4; ++nj) xb[nj] = ld8(&Xb[swzi((nj << 4) + lo, kk, 256)]);
#pragma unroll
      for (int m = 0; m < 4; ++m)
#pragma unroll
        for (int nj = 0; nj < 4; ++nj)
          acc[m][nj] = __builtin_amdgcn_mfma_f32_16x16x32_bf16(bwr[ks & 1][m], xb[nj], acc[m][nj], 0, 0, 0);
    }
    const float* bias = (ph == 0) ? Qbv : Kbv;
    const float scale = (ph == 0) ? 0.17677669529663687f * LOG2E : 1.0f;  // hd^-0.5*log2e on q
#pragma unroll
    for (int m = 0; m < 4; ++m) {
      const float4 bb = *reinterpret_cast<const float4*>(bias + (wid << 6) + (m << 4) + g4);
#pragma unroll
      for (int nj = 0; nj < 4; ++nj) {
        const bf16x4_t v = pack4((acc[m][nj][0] + bb.x) * scale, (acc[m][nj][1] + bb.y) * scale,
                                 (acc[m][nj][2] + bb.z) * scale, (acc[m][nj][3] + bb.w) * scale);
        if (ph == 0) qf[m][nj] = v; else kf[m][nj] = v;
      }
    }
    XWRITE(ph ^ 1);     // K -> buf1 (while Q GEMM read buf0), V -> buf0
    __syncthreads();
  }

  // ---------------- V projection (unswapped: D[tok][ch]) from buf0 ----------------
  {
    const unsigned short* Xb = Xs[0];
    const unsigned short* W_ = wbf + (2 << 16);
    f32x4_t acc[4][4];
#pragma unroll
    for (int a = 0; a < 4; ++a)
#pragma unroll
      for (int c = 0; c < 4; ++c) acc[a][c] = (f32x4_t){0.f, 0.f, 0.f, 0.f};
    WLOAD(W_, 0, 0);
#pragma unroll
    for (int ks = 0; ks < 8; ++ks) {
      if (ks < 7) WLOAD(W_, ks + 1, (ks + 1) & 1);
      const int kk = (ks << 5) + kof;
      bf16x8_t xa[4];
#pragma unroll
      for (int mi = 0; mi < 4; ++mi) xa[mi] = ld8(&Xb[swzi((mi << 4) + lo, kk, 256)]);
#pragma unroll
      for (int mi = 0; mi < 4; ++mi)
#pragma unroll
        for (int t = 0; t < 4; ++t)
          acc[mi][t] = __builtin_amdgcn_mfma_f32_16x16x32_bf16(xa[mi], bwr[ks & 1][t], acc[mi][t], 0, 0, 0);
    }
    float bbv[4];
#pragma unroll
    for (int t = 0; t < 4; ++t) bbv[t] = Vbv[(wid << 6) + (t << 4) + lo];
#pragma unroll
    for (int mi = 0; mi < 4; ++mi)
#pragma unroll
      for (int t = 0; t < 4; ++t)
        vf[mi][t] = pack4(acc[mi][t][0] + bbv[t], acc[mi][t][1] + bbv[t],
                          acc[mi][t][2] + bbv[t], acc[mi][t][3] + bbv[t]);
  }

  // ---------------- attention, fully in registers (2 heads per wave) ----------------
  const bool wi15 = (wi == 15), wj15 = (wj == 15);
  // key-token bits per (njk, rg): kt = 16*njk + 4*hi + rg
  unsigned kbi = 0, kbj = 0, kval = 0;
#pragma unroll
  for (int njk = 0; njk < 4; ++njk)
#pragma unroll
    for (int rg = 0; rg < 4; ++rg) {
      int kt = (njk << 4) + g4 + rg;
      if (kt < NTOK) {
        int ti = kt / 7, tj = kt - (kt / 7) * 7;
        unsigned bit = 1u << (njk * 4 + rg);
        kval |= bit;
        if (ti >= 4) kbi |= bit;
        if (tj >= 4) kbj |= bit;
      }
    }

#pragma unroll
  for (int hh = 0; hh < 2; ++hh) {
    const int h = (wid << 1) + hh;
    const int co = h << 5;

    // per-column S^T + softmax -> pf (R7-verified shape)
    bf16x4_t pf[4][4];
#pragma unroll
    for (int njq = 0; njq < 4; ++njq) {
      const int qt = (njq << 4) + lo;
      const bool qv = qt < NTOK;
      const int sqt = qv ? qt : 0;
      const float* bq = biasP + h * 3136 + (sqt << 6);
      f32x4_t bfr[4];
#pragma unroll
      for (int njk = 0; njk < 4; ++njk)
        bfr[njk] = *reinterpret_cast<const f32x4_t*>(bq + (njk << 4) + g4);

      f32x4_t stc[4];
      __builtin_amdgcn_s_setprio(1);
#pragma unroll
      for (int njk = 0; njk < 4; ++njk) {
        stc[njk] = __builtin_amdgcn_mfma_f32_16x16x16bf16_1k(
            kf[(hh << 1)][njk], qf[(hh << 1)][njq], (f32x4_t){0.f, 0.f, 0.f, 0.f}, 0, 0, 0);
        stc[njk] = __builtin_amdgcn_mfma_f32_16x16x16bf16_1k(
            kf[(hh << 1) + 1][njk], qf[(hh << 1) + 1][njq], stc[njk], 0, 0, 0);
      }
      __builtin_amdgcn_s_setprio(0);

      const int qti = sqt / 7, qtj = sqt - (sqt / 7) * 7;
      const bool qbi = qti >= 4, qbj = qtj >= 4;
      float m = -3e38f;
#pragma unroll
      for (int njk = 0; njk < 4; ++njk)
#pragma unroll
        for (int rg = 0; rg < 4; ++rg) {
          const int bit = njk * 4 + rg;
          const bool valid = qv && ((kval >> bit) & 1u);
          float v = stc[njk][rg] + bfr[njk][rg];
          if (wi15 && (qbi != (bool)((kbi >> bit) & 1u))) v += MASKS;
          if (wj15 && (qbj != (bool)((kbj >> bit) & 1u))) v += MASKS;
          v = valid ? v : -1e30f;
          stc[njk][rg] = v;
          m = fmaxf(m, v);
        }
      m = fmaxf(m, __shfl_xor(m, 16));
      m = fmaxf(m, __shfl_xor(m, 32));
      float sum = 0.f;
#pragma unroll
      for (int njk = 0; njk < 4; ++njk)
#pragma unroll
        for (int rg = 0; rg < 4; ++rg) {
          const float e = exp2fast(stc[njk][rg] - m);
          stc[njk][rg] = e;
          sum += e;
        }
      sum += __shfl_xor(sum, 16);
      sum += __shfl_xor(sum, 32);
      const float inv = __builtin_amdgcn_rcpf(sum);
#pragma unroll
      for (int njk = 0; njk < 4; ++njk)
        pf[njk][njq] = pack4(stc[njk][0] * inv, stc[njk][1] * inv,
                             stc[njk][2] * inv, stc[njk][3] * inv);
    }

    // PV: O^T[ch][qt] = sum_kt V^T[ch][kt] P^T[kt][qt]
    f32x4_t o[2][4];
#pragma unroll
    for (int a = 0; a < 2; ++a)
#pragma unroll
      for (int c = 0; c < 4; ++c) o[a][c] = (f32x4_t){0.f, 0.f, 0.f, 0.f};
    __builtin_amdgcn_s_setprio(1);
#pragma unroll
    for (int mi = 0; mi < 4; ++mi)
#pragma unroll
      for (int t2 = 0; t2 < 2; ++t2)
#pragma unroll
        for (int njq = 0; njq < 4; ++njq)
          o[t2][njq] = __builtin_amdgcn_mfma_f32_16x16x16bf16_1k(
              vf[mi][(hh << 1) + t2], pf[mi][njq], o[t2][njq], 0, 0, 0);
    __builtin_amdgcn_s_setprio(0);

    // attn-out -> Xs[1] (buf1's last readers finished before the pre-V barrier)
#pragma unroll
    for (int t2 = 0; t2 < 2; ++t2)
#pragma unroll
      for (int njq = 0; njq < 4; ++njq) {
        const int qt = (njq << 4) + lo;
        const int ch0 = co + (t2 << 4) + g4;
        *reinterpret_cast<uint2*>(&Xs[1][swzi(qt, ch0, 256)]) =
            make_uint2(cvtpk(o[t2][njq][0], o[t2][njq][1]),
                       cvtpk(o[t2][njq][2], o[t2][njq][3]));
      }
  }
  __syncthreads();

  // ---------------- final projection (swapped) + scatter with inverse roll ----------------
  {
    const unsigned short* Xb = Xs[1];
    const unsigned short* W_ = wbf + (3 << 16);
    f32x4_t y[4][4];
#pragma unroll
    for (int a = 0; a < 4; ++a)
#pragma unroll
      for (int c = 0; c < 4; ++c) y[a][c] = (f32x4_t){0.f, 0.f, 0.f, 0.f};
    WLOAD(W_, 0, 0);
#pragma unroll
    for (int ks = 0; ks < 8; ++ks) {
      if (ks < 7) WLOAD(W_, ks + 1, (ks + 1) & 1);
      const int kk = (ks << 5) + kof;
      bf16x8_t xb[4];
#pragma unroll
      for (int nj = 0; nj < 4; ++nj) xb[nj] = ld8(&Xb[swzi((nj << 4) + lo, kk, 256)]);
#pragma unroll
      for (int m = 0; m < 4; ++m)
#pragma unroll
        for (int nj = 0; nj < 4; ++nj)
          y[m][nj] = __builtin_amdgcn_mfma_f32_16x16x32_bf16(bwr[ks & 1][m], xb[nj], y[m][nj], 0, 0, 0);
    }
#pragma unroll
    for (int nj = 0; nj < 4; ++nj) {
      const int tok = (nj << 4) + lo;
      if (tok < NTOK) {
        const int i = tok / 7, j = tok - (tok / 7) * 7;
        int h_ = wi * 7 + i + SHIFT; if (h_ >= HH) h_ -= HH;
        int w_ = wj * 7 + j + SHIFT; if (w_ >= WWDIM) w_ -= WWDIM;
        float* ob = out + ((size_t)((b * HH + h_) * WWDIM + w_) << 8);
#pragma unroll
        for (int m = 0; m < 4; ++m) {
          const int ch0 = (wid << 6) + (m << 4) + g4;
          const float4 pb = *reinterpret_cast<const float4*>(Pbv + ch0);
          *reinterpret_cast<float4*>(ob + ch0) =
              make_float4(y[m][nj][0] + pb.x, y[m][nj][1] + pb.y,
                          y[m][nj][2] + pb.z, y[m][nj][3] + pb.w);
        }
      }
    }
  }
}

extern "C" void kernel_launch(void* const* d_in, const int* in_sizes, int n_in,
                              void* d_out, int out_size, void* d_ws, size_t ws_size,
                              hipStream_t stream) {
  const float* Q   = (const float*)d_in[0];
  const float* K   = (const float*)d_in[1];
  const float* V   = (const float*)d_in[2];
  const float* Qw  = (const float*)d_in[3];
  const float* Qb  = (const float*)d_in[4];
  const float* Kw  = (const float*)d_in[5];
  const float* Kb  = (const float*)d_in[6];
  const float* Vw  = (const float*)d_in[7];
  const float* Vb  = (const float*)d_in[8];
  const float* Pw  = (const float*)d_in[9];
  const float* Pb  = (const float*)d_in[10];
  const float* rpb = (const float*)d_in[11];
  const int*   rpi = (const int*)d_in[12];

  unsigned short* wbf = (unsigned short*)d_ws;                 // 4*65536 bf16
  float* biasP = (float*)(wbf + 4 * 65536);                    // 8*49*64 f32, log2e-scaled

  const size_t need = (size_t)4 * 65536 * 2 + (size_t)8 * 49 * 64 * 4;
  if (ws_size < need) return;  // loud failure signal (output stays poisoned)

  prep_kernel<<<1024, 256, 0, stream>>>(Qw, Kw, Vw, Pw, rpb, rpi, wbf, biasP);
  fused_kernel<<<NWIN, 256, 0, stream>>>(Q, K, V, Qb, Kb, Vb, Pb, wbf, biasP,
                                         (float*)d_out);
}